// Round 1
// baseline (24.821 us; speedup 1.0000x reference)
//
#include <hip/hip_runtime.h>

#define PCL_EPS 1e-6f
#define N_PROP 262144
#define N_PC 4096
#define N_CLS 81

__global__ __launch_bounds__(256) void pcl_reduce_kernel(
    const float* __restrict__ pcl_prob,    // [N_PROP, N_CLS]
    const int*   __restrict__ labels,      // [N_PROP]
    const float* __restrict__ clw,         // [N_PROP]
    const int*   __restrict__ pc_labels,   // [N_PC]
    const float* __restrict__ pc_probs,    // [N_PC]
    const float* __restrict__ pc_count,    // [N_PC]
    const float* __restrict__ img_w,       // [N_PC]
    const float* __restrict__ im_real,     // [N_CLS]
    double*      __restrict__ acc)
{
    const int i = blockIdx.x * blockDim.x + threadIdx.x;
    double s = 0.0;

    if (i < N_PROP) {
        // Background term: only read pcl_prob/clw when the (rare) mask hits,
        // so the stride-81 pcl_prob column gather only fetches ~1/81 of rows.
        const int lab = labels[i];
        if (lab == 0 && im_real[0] > 0.0f) {
            const float p = pcl_prob[(size_t)i * N_CLS];  // column 0
            s = (double)(clw[i] * logf(fmaxf(p, PCL_EPS)));
        }
    } else {
        const int j = i - N_PROP;
        if (j < N_PC) {
            const int c = pc_labels[j];
            if (c > 0 && im_real[c] > 0.0f) {
                s = (double)(pc_count[j] * img_w[j] *
                             logf(fmaxf(pc_probs[j], PCL_EPS)));
            }
        }
    }

    // 64-lane wave reduction (double via paired 32-bit shuffles)
    #pragma unroll
    for (int off = 32; off > 0; off >>= 1)
        s += __shfl_down(s, off, 64);

    __shared__ double wsum[4];
    const int lane = threadIdx.x & 63;
    const int wid  = threadIdx.x >> 6;
    if (lane == 0) wsum[wid] = s;
    __syncthreads();

    if (threadIdx.x == 0) {
        const double t = wsum[0] + wsum[1] + wsum[2] + wsum[3];
        if (t != 0.0) atomicAdd(acc, t);
    }
}

__global__ void pcl_finalize_kernel(const double* __restrict__ acc,
                                    float* __restrict__ out)
{
    out[0] = (float)(-acc[0] / (double)N_PROP);
}

extern "C" void kernel_launch(void* const* d_in, const int* in_sizes, int n_in,
                              void* d_out, int out_size, void* d_ws, size_t ws_size,
                              hipStream_t stream) {
    const float* pcl_prob  = (const float*)d_in[0];
    const int*   labels    = (const int*)  d_in[1];
    const float* clw       = (const float*)d_in[2];
    // d_in[3] = gt_assignment (unused by the reference)
    const int*   pc_labels = (const int*)  d_in[4];
    const float* pc_probs  = (const float*)d_in[5];
    const float* pc_count  = (const float*)d_in[6];
    const float* img_w     = (const float*)d_in[7];
    const float* im_real   = (const float*)d_in[8];
    float*       out       = (float*)d_out;
    double*      acc       = (double*)d_ws;

    // Zero the accumulator every call (ws is NOT re-poisoned between replays).
    hipMemsetAsync(acc, 0, sizeof(double), stream);

    const int total  = N_PROP + N_PC;
    const int blocks = (total + 255) / 256;
    pcl_reduce_kernel<<<blocks, 256, 0, stream>>>(
        pcl_prob, labels, clw, pc_labels, pc_probs, pc_count, img_w, im_real, acc);

    pcl_finalize_kernel<<<1, 1, 0, stream>>>(acc, out);
}

// Round 2
// 12.031 us; speedup vs baseline: 2.0631x; 2.0631x over previous
//
#include <hip/hip_runtime.h>

#define PCL_EPS 1e-6f
#define N_PROP 262144
#define N_PC 4096
#define N_CLS 81
#define BLOCK 256
#define TOTAL (N_PROP + N_PC)
#define NBLOCKS ((TOTAL + BLOCK - 1) / BLOCK)   // 1040

__global__ __launch_bounds__(BLOCK) void pcl_reduce_kernel(
    const float* __restrict__ pcl_prob,    // [N_PROP, N_CLS]
    const int*   __restrict__ labels,      // [N_PROP]
    const float* __restrict__ clw,         // [N_PROP]
    const int*   __restrict__ pc_labels,   // [N_PC]
    const float* __restrict__ pc_probs,    // [N_PC]
    const float* __restrict__ pc_count,    // [N_PC]
    const float* __restrict__ img_w,       // [N_PC]
    const float* __restrict__ im_real,     // [N_CLS]
    double*      __restrict__ partials)    // [NBLOCKS]
{
    const int i = blockIdx.x * BLOCK + threadIdx.x;
    double s = 0.0;

    if (i < N_PROP) {
        // BG term: only touch pcl_prob/clw when label==0 (~1/81 of rows),
        // so the stride-324B column-0 gather fetches ~1/81 of the lines.
        const int lab = labels[i];
        if (lab == 0 && im_real[0] > 0.0f) {
            const float p = pcl_prob[(size_t)i * N_CLS];  // column 0
            s = (double)(clw[i] * logf(fmaxf(p, PCL_EPS)));
        }
    } else if (i < TOTAL) {
        const int j = i - N_PROP;
        const int c = pc_labels[j];
        if (c > 0 && im_real[c] > 0.0f) {
            s = (double)(pc_count[j] * img_w[j] *
                         logf(fmaxf(pc_probs[j], PCL_EPS)));
        }
    }

    // 64-lane wave reduction
    #pragma unroll
    for (int off = 32; off > 0; off >>= 1)
        s += __shfl_down(s, off, 64);

    __shared__ double wsum[BLOCK / 64];
    const int lane = threadIdx.x & 63;
    const int wid  = threadIdx.x >> 6;
    if (lane == 0) wsum[wid] = s;
    __syncthreads();

    if (threadIdx.x == 0) {
        // Plain store — every slot written every call, no init required.
        partials[blockIdx.x] = wsum[0] + wsum[1] + wsum[2] + wsum[3];
    }
}

__global__ __launch_bounds__(256) void pcl_finalize_kernel(
    const double* __restrict__ partials,
    float* __restrict__ out)
{
    double s = 0.0;
    for (int i = threadIdx.x; i < NBLOCKS; i += 256)
        s += partials[i];

    #pragma unroll
    for (int off = 32; off > 0; off >>= 1)
        s += __shfl_down(s, off, 64);

    __shared__ double wsum[4];
    const int lane = threadIdx.x & 63;
    const int wid  = threadIdx.x >> 6;
    if (lane == 0) wsum[wid] = s;
    __syncthreads();

    if (threadIdx.x == 0) {
        const double t = wsum[0] + wsum[1] + wsum[2] + wsum[3];
        out[0] = (float)(-t / (double)N_PROP);
    }
}

extern "C" void kernel_launch(void* const* d_in, const int* in_sizes, int n_in,
                              void* d_out, int out_size, void* d_ws, size_t ws_size,
                              hipStream_t stream) {
    const float* pcl_prob  = (const float*)d_in[0];
    const int*   labels    = (const int*)  d_in[1];
    const float* clw       = (const float*)d_in[2];
    // d_in[3] = gt_assignment (unused by the reference)
    const int*   pc_labels = (const int*)  d_in[4];
    const float* pc_probs  = (const float*)d_in[5];
    const float* pc_count  = (const float*)d_in[6];
    const float* img_w     = (const float*)d_in[7];
    const float* im_real   = (const float*)d_in[8];
    float*       out       = (float*)d_out;
    double*      partials  = (double*)d_ws;

    pcl_reduce_kernel<<<NBLOCKS, BLOCK, 0, stream>>>(
        pcl_prob, labels, clw, pc_labels, pc_probs, pc_count, img_w, im_real,
        partials);

    pcl_finalize_kernel<<<1, 256, 0, stream>>>(partials, out);
}